// Round 12
// baseline (134.951 us; speedup 1.0000x reference)
//
#include <hip/hip_runtime.h>
#include <hip/hip_bf16.h>
#include <cstdint>
#include <cmath>

// Shapes (hard-coded): B=4, S=4096, D=1024, DK=DV=128.
// ws layout: Qb[16384][128]bf16 @0 (4MB) | Kb @4MB | Vt[B][128][4096]bf16 @8MB
//            | Wtq bf16[128][1024] @12MB | Wtk | Wtv (ends 12.75MB)
//            | Po[nsplit][16384][128]f32 @13MB | ml[nsplit][16384][2]f32 after.

typedef __bf16 bf16x8 __attribute__((ext_vector_type(8)));
typedef float f32x4 __attribute__((ext_vector_type(4)));
typedef float f32x16 __attribute__((ext_vector_type(16)));

typedef const __attribute__((address_space(1))) unsigned int* gp_t;
typedef __attribute__((address_space(3))) unsigned int* lp_t;

__device__ __forceinline__ unsigned short f2bf(float f) {
  unsigned u = __float_as_uint(f);
  u += 0x7fffu + ((u >> 16) & 1u);   // RNE
  return (unsigned short)(u >> 16);
}

__device__ __forceinline__ bf16x8 ld_frag(const char* p) {
  uint4 u = *reinterpret_cast<const uint4*>(p);
  return __builtin_bit_cast(bf16x8, u);
}

__device__ __forceinline__ unsigned cvtpk_bf16(float lo, float hi) {
  unsigned r;
  asm("v_cvt_pk_bf16_f32 %0, %1, %2" : "=v"(r) : "v"(lo), "v"(hi));
  return r;
}

__device__ __forceinline__ void pl32swap(unsigned &a, unsigned &b) {
  asm("v_permlane32_swap_b32 %0, %1" : "+v"(a), "+v"(b));
}

__device__ __forceinline__ bf16x8 mk_frag(unsigned w0, unsigned w1, unsigned w2, unsigned w3) {
  uint4 u{w0, w1, w2, w3};
  return __builtin_bit_cast(bf16x8, u);
}

// Q is pre-scaled by (1/sqrt(128)) * log2(e) so softmax uses exp2 directly.
#define QSCALE_LOG2E 0.12751744f

// ---------------- diagnostic/prime: stream all of q,k,v (192MB) -------------
// Measures the d_in read ceiling AND primes L3 for proj. Output (8MB) goes to
// the Po region, which attn fully overwrites before combine reads it.
__global__ __launch_bounds__(256) void prime_kernel(const uint4* __restrict__ q,
                                                    const uint4* __restrict__ k,
                                                    const uint4* __restrict__ v,
                                                    uint4* __restrict__ outp) {
  const int t = blockIdx.x * 256 + threadIdx.x;   // 524288 threads
  uint4 acc{0u, 0u, 0u, 0u};
#pragma unroll
  for (int i = 0; i < 8; ++i) {
    uint4 a = q[t + i * 524288];
    acc.x ^= a.x; acc.y ^= a.y; acc.z ^= a.z; acc.w ^= a.w;
  }
#pragma unroll
  for (int i = 0; i < 8; ++i) {
    uint4 a = k[t + i * 524288];
    acc.x ^= a.x; acc.y ^= a.y; acc.z ^= a.z; acc.w ^= a.w;
  }
#pragma unroll
  for (int i = 0; i < 8; ++i) {
    uint4 a = v[t + i * 524288];
    acc.x ^= a.x; acc.y ^= a.y; acc.z ^= a.z; acc.w ^= a.w;
  }
  outp[t] = acc;
}

// ---------------- W transpose: [1024][128] f32 -> [128][1024] bf16 ----------
__global__ __launch_bounds__(256) void prep_wt_kernel(
    const float* __restrict__ W0, const float* __restrict__ W1, const float* __restrict__ W2,
    unsigned short* __restrict__ T0, unsigned short* __restrict__ T1,
    unsigned short* __restrict__ T2) {
  const int mode = blockIdx.z;
  const float* W = (mode == 0) ? W0 : (mode == 1) ? W1 : W2;
  unsigned short* Wt = (mode == 0) ? T0 : (mode == 1) ? T1 : T2;
  __shared__ float tile[64][65];
  int kt = blockIdx.x, nt = blockIdx.y;   // (16, 2)
  int tid = threadIdx.x;
  int c = tid & 63;
  int r0 = (tid >> 6) * 16;
#pragma unroll
  for (int i = 0; i < 16; ++i) {
    int r = r0 + i;
    tile[r][c] = W[(size_t)(kt * 64 + r) * 128 + nt * 64 + c];
  }
  __syncthreads();
#pragma unroll
  for (int i = 0; i < 16; ++i) {
    int n = r0 + i;
    Wt[(size_t)(nt * 64 + n) * 1024 + kt * 64 + c] = f2bf(tile[c][n]);
  }
}

// ---------------- projections (round-11 fat-step structure) -----------------
__global__ __launch_bounds__(256, 3) void proj_kernel(
    const float* __restrict__ qx, const float* __restrict__ kx, const float* __restrict__ vx,
    const unsigned short* __restrict__ Wtq, const unsigned short* __restrict__ Wtk,
    const unsigned short* __restrict__ Wtv,
    const float* __restrict__ bq, const float* __restrict__ bk, const float* __restrict__ bv,
    unsigned short* __restrict__ Qb, unsigned short* __restrict__ Kb,
    unsigned short* __restrict__ Vtb) {
  const int mode = blockIdx.y;  // 0=Q 1=K 2=V
  const float* x = (mode == 0) ? qx : (mode == 1) ? kx : vx;
  const unsigned short* Wt = (mode == 0) ? Wtq : (mode == 1) ? Wtk : Wtv;
  const float* bias = (mode == 0) ? bq : (mode == 1) ? bk : bv;

  __shared__ __align__(16) char lds[49152];
  char* ldsA = lds;            // [64 rows][128 k] bf16, 16KB, XOR-swizzled
  char* ldsW = lds + 16384;    // [128 n][128 k] bf16, 32KB, XOR-swizzled

  const int tid = threadIdx.x;
  const int lane = tid & 63, wid = tid >> 6;
  const int l15 = lane & 15, hi = lane >> 4;
  const long row0 = (long)blockIdx.x * 64;

  const int a_row0 = tid >> 5;
  const int a_c16  = tid & 31;
  const float* a_src = x + (row0 + a_row0) * 1024 + a_c16 * 4;
  const int a_swz = (a_row0 & 7) << 4;
  const int a_wbyte = (((a_c16 >> 1) * 16) ^ a_swz) + (a_c16 & 1) * 8;

  const char* w_src = (const char*)Wt + (size_t)(tid >> 4) * 2048 +
                      (size_t)((tid & 15) ^ ((tid >> 4) & 7)) * 16;

  f32x4 acc[8];
#pragma unroll
  for (int i = 0; i < 8; ++i) acc[i] = f32x4{0.f, 0.f, 0.f, 0.f};

  const int arow = wid * 16 + l15;
  const int aswzr = (arow & 7) << 4;

#pragma unroll 1
  for (int t = 0; t < 8; ++t) {
    float4 av[8];
#pragma unroll
    for (int j = 0; j < 8; ++j)
      av[j] = *reinterpret_cast<const float4*>(a_src + t * 128 + j * 8192);
#pragma unroll
    for (int i = 0; i < 8; ++i)
      __builtin_amdgcn_global_load_lds((gp_t)(w_src + (size_t)i * 32768 + t * 256),
                                       (lp_t)(ldsW + i * 4096 + wid * 1024), 16, 0, 0);
#pragma unroll
    for (int j = 0; j < 8; ++j) {
      uint2 wv;
      wv.x = cvtpk_bf16(av[j].x, av[j].y);
      wv.y = cvtpk_bf16(av[j].z, av[j].w);
      *reinterpret_cast<uint2*>(ldsA + a_row0 * 256 + j * 2048 + a_wbyte) = wv;
    }
    __syncthreads();

    bf16x8 af[4];
#pragma unroll
    for (int kk = 0; kk < 4; ++kk)
      af[kk] = ld_frag(ldsA + ((arow * 256 + (kk * 4 + hi) * 16) ^ aswzr));
#pragma unroll
    for (int ni = 0; ni < 8; ++ni) {
      int n = ni * 16 + l15;
      int nswz = (n & 7) << 4;
#pragma unroll
      for (int kk = 0; kk < 4; ++kk) {
        bf16x8 wf = ld_frag(ldsW + ((n * 256 + (kk * 4 + hi) * 16) ^ nswz));
        acc[ni] = __builtin_amdgcn_mfma_f32_16x16x32_bf16(af[kk], wf, acc[ni], 0, 0, 0);
      }
    }
    __syncthreads();
  }

#pragma unroll
  for (int ni = 0; ni < 8; ++ni) {
    int n = ni * 16 + l15;
    float bv_ = bias[n];
    long m = row0 + wid * 16 + hi * 4;
    f32x4 a = acc[ni];
    if (mode == 2) {
      int bb = (int)(m >> 12);
      int s = (int)(m & 4095);
      ushort4 pk;
      pk.x = f2bf(a.x + bv_); pk.y = f2bf(a.y + bv_);
      pk.z = f2bf(a.z + bv_); pk.w = f2bf(a.w + bv_);
      *reinterpret_cast<ushort4*>(Vtb + ((size_t)(bb * 128 + n)) * 4096 + s) = pk;
    } else {
      const float sc = (mode == 0) ? QSCALE_LOG2E : 1.0f;
      unsigned short* outp = (mode == 0) ? Qb : Kb;
      outp[(m + 0) * 128 + n] = f2bf((a.x + bv_) * sc);
      outp[(m + 1) * 128 + n] = f2bf((a.y + bv_) * sc);
      outp[(m + 2) * 128 + n] = f2bf((a.z + bv_) * sc);
      outp[(m + 3) * 128 + n] = f2bf((a.w + bv_) * sc);
    }
  }
}

// ---------------- flash attention (32x32 swapped, dbuf K/V + counted vmcnt) -
template <int TPS>
__global__ __launch_bounds__(256, 2) void attn_kernel(
    const unsigned short* __restrict__ Qb, const unsigned short* __restrict__ Kb,
    const unsigned short* __restrict__ Vtb, float* __restrict__ Po,
    float* __restrict__ ml) {
  __shared__ __align__(16) char lds[65536];  // K: 2x16KB @0, V: 2x16KB @32768

  const int tid = threadIdx.x;
  const int lane = tid & 63, wid = tid >> 6;
  const int l31 = lane & 31, hi = lane >> 5;
  const int split = blockIdx.y;
  const int b = blockIdx.z;
  const int qbase = blockIdx.x * 128 + wid * 32;  // within batch
  const size_t growq = (size_t)b * 4096 + qbase + l31;

  const char* kg0 = (const char*)Kb + (size_t)(b * 4096) * 256;
  const char* vg0 = (const char*)Vtb + (size_t)b * 128 * 4096 * 2;
  const int k_row = tid >> 4;
  const int k_csw = (tid & 15) ^ (k_row & 7);
  const int v_dv = tid >> 3;
  const int v_csw = (tid & 7) ^ (v_dv & 7);

#define ATTN_STAGE(KV0, BUF)                                                          \
  {                                                                                   \
    char* kb_ = lds + (BUF) * 16384;                                                  \
    char* vb_ = lds + 32768 + (BUF) * 16384;                                          \
    const char* kgs_ = kg0 + (size_t)(KV0) * 256 + (size_t)k_row * 256 + k_csw * 16;  \
    const char* vgs_ = vg0 + (size_t)(KV0) * 2 + (size_t)v_dv * 8192 + v_csw * 16;    \
    _Pragma("unroll")                                                                 \
    for (int i = 0; i < 4; ++i)                                                       \
      __builtin_amdgcn_global_load_lds((gp_t)(kgs_ + (size_t)i * 4096),               \
                                       (lp_t)(kb_ + i * 4096 + wid * 1024), 16, 0, 0);\
    _Pragma("unroll")                                                                 \
    for (int i = 0; i < 4; ++i)                                                       \
      __builtin_amdgcn_global_load_lds((gp_t)(vgs_ + (size_t)i * 262144),             \
                                       (lp_t)(vb_ + i * 4096 + wid * 1024), 16, 0, 0);\
  }

  bf16x8 qf[8];
  {
    const unsigned short* qp = Qb + growq * 128 + hi * 8;
#pragma unroll
    for (int kt = 0; kt < 8; ++kt)
      qf[kt] = __builtin_bit_cast(bf16x8, *reinterpret_cast<const uint4*>(qp + kt * 16));
  }

  f32x16 oacc[4];
#pragma unroll
  for (int d = 0; d < 4; ++d)
#pragma unroll
    for (int j = 0; j < 16; ++j) oacc[d][j] = 0.f;
  float mrun = -INFINITY, lrun = 0.f;

  const int t0 = split * TPS, t1 = t0 + TPS;

  ATTN_STAGE(t0 * 64, 0);
  ATTN_STAGE((t0 + 1) * 64, 1);

#pragma unroll 1
  for (int t = t0; t < t1; ++t) {
    const int buf = (t - t0) & 1;
    if (t < t1 - 1) asm volatile("s_waitcnt vmcnt(8)" ::: "memory");
    else            asm volatile("s_waitcnt vmcnt(0)" ::: "memory");
    __builtin_amdgcn_s_barrier();
    __builtin_amdgcn_sched_barrier(0);
    char* ldsK = lds + buf * 16384;
    char* ldsV = lds + 32768 + buf * 16384;

    f32x16 sc0, sc1;
#pragma unroll
    for (int j = 0; j < 16; ++j) { sc0[j] = 0.f; sc1[j] = 0.f; }
    __builtin_amdgcn_s_setprio(1);
#pragma unroll
    for (int kvb = 0; kvb < 2; ++kvb) {
      int row = kvb * 32 + l31;
      int rowoff = row * 256, swz = (row & 7) << 4;
#pragma unroll
      for (int kt = 0; kt < 8; ++kt) {
        bf16x8 kf = ld_frag(ldsK + ((rowoff + kt * 32 + hi * 16) ^ swz));
        if (kvb == 0) sc0 = __builtin_amdgcn_mfma_f32_32x32x16_bf16(kf, qf[kt], sc0, 0, 0, 0);
        else          sc1 = __builtin_amdgcn_mfma_f32_32x32x16_bf16(kf, qf[kt], sc1, 0, 0, 0);
      }
    }
    __builtin_amdgcn_s_setprio(0);

    float tmx[16];
#pragma unroll
    for (int i = 0; i < 16; ++i) tmx[i] = fmaxf(sc0[i], sc1[i]);
#pragma unroll
    for (int s = 8; s > 0; s >>= 1)
#pragma unroll
      for (int i = 0; i < s; ++i) tmx[i] = fmaxf(tmx[i], tmx[i + s]);
    float mt = tmx[0];
    mt = fmaxf(mt, __shfl_xor(mt, 32));

    if (!__all(mt - mrun <= 8.0f)) {
      float mnew = fmaxf(mrun, mt);
      float scl = exp2f(mrun - mnew);
      mrun = mnew;
      lrun *= scl;
#pragma unroll
      for (int d = 0; d < 4; ++d)
#pragma unroll
        for (int j = 0; j < 16; ++j) oacc[d][j] *= scl;
    }

#pragma unroll
    for (int i = 0; i < 16; ++i) {
      sc0[i] = exp2f(sc0[i] - mrun);
      sc1[i] = exp2f(sc1[i] - mrun);
    }
    float ts[16];
#pragma unroll
    for (int i = 0; i < 16; ++i) ts[i] = sc0[i] + sc1[i];
#pragma unroll
    for (int s = 8; s > 0; s >>= 1)
#pragma unroll
      for (int i = 0; i < s; ++i) ts[i] += ts[i + s];
    float psum = ts[0];
    psum += __shfl_xor(psum, 32);
    lrun += psum;

    bf16x8 pa[4];
#pragma unroll
    for (int c = 0; c < 2; ++c) {
      const f32x16& p = c ? sc1 : sc0;
#pragma unroll
      for (int g = 0; g < 2; ++g) {
        const int base = g * 8;
        unsigned a0 = cvtpk_bf16(p[base + 0], p[base + 1]);
        unsigned b0 = cvtpk_bf16(p[base + 4], p[base + 5]);
        pl32swap(a0, b0);
        unsigned a1 = cvtpk_bf16(p[base + 2], p[base + 3]);
        unsigned b1 = cvtpk_bf16(p[base + 6], p[base + 7]);
        pl32swap(a1, b1);
        pa[c * 2 + g] = mk_frag(a0, a1, b0, b1);
      }
    }

    __builtin_amdgcn_s_setprio(1);
#pragma unroll
    for (int dvb = 0; dvb < 4; ++dvb) {
      int vrow = dvb * 32 + l31;
      int voff = vrow * 128, vswz = (vrow & 7) << 4;
#pragma unroll
      for (int tt = 0; tt < 4; ++tt) {
        bf16x8 vf = ld_frag(ldsV + ((voff + tt * 32 + hi * 16) ^ vswz));
        oacc[dvb] = __builtin_amdgcn_mfma_f32_32x32x16_bf16(vf, pa[tt], oacc[dvb], 0, 0, 0);
      }
    }
    __builtin_amdgcn_s_setprio(0);

    __builtin_amdgcn_s_barrier();
    __builtin_amdgcn_sched_barrier(0);
    if (t + 2 < t1) ATTN_STAGE((t + 2) * 64, buf);
  }

#undef ATTN_STAGE

  if (hi == 0) {
    float* mlp = ml + (size_t)split * 32768 + growq * 2;
    mlp[0] = mrun; mlp[1] = lrun;
  }

  float* po = Po + ((size_t)split << 21) + ((size_t)b * 4096 + qbase) * 128;
  char* tbase = lds + wid * 4096;
  for (int dvb = 0; dvb < 4; ++dvb) {
#pragma unroll
    for (int g = 0; g < 4; ++g) {
      float4 w4{oacc[dvb][g * 4 + 0], oacc[dvb][g * 4 + 1],
                oacc[dvb][g * 4 + 2], oacc[dvb][g * 4 + 3]};
      int off = (l31 * 128 + g * 32 + hi * 16) ^ ((l31 & 7) << 4);
      *reinterpret_cast<float4*>(tbase + off) = w4;
    }
    asm volatile("s_waitcnt lgkmcnt(0)" ::: "memory");
    __builtin_amdgcn_sched_barrier(0);
#pragma unroll
    for (int qq = 0; qq < 4; ++qq) {
      int q = qq * 8 + (lane >> 3);
      int off = (q * 128 + (lane & 7) * 16) ^ ((q & 7) << 4);
      float4 r4 = *reinterpret_cast<const float4*>(tbase + off);
      *reinterpret_cast<float4*>(po + (size_t)q * 128 + dvb * 32 + (lane & 7) * 4) = r4;
    }
    asm volatile("s_waitcnt lgkmcnt(0)" ::: "memory");
    __builtin_amdgcn_sched_barrier(0);
  }
}

// ---------------- combine partials ------------------------------------------
template <int NS>
__global__ __launch_bounds__(256) void combine_kernel(const float* __restrict__ Po,
                                                      const float* __restrict__ ml,
                                                      float* __restrict__ out) {
  int idx = blockIdx.x * 256 + threadIdx.x;
  int grow = idx >> 5;
  int c4 = (idx & 31) * 4;
  float m[NS], l[NS];
  float M = -INFINITY;
#pragma unroll
  for (int s = 0; s < NS; ++s) {
    m[s] = ml[(size_t)s * 32768 + grow * 2 + 0];
    l[s] = ml[(size_t)s * 32768 + grow * 2 + 1];
    M = fmaxf(M, m[s]);
  }
  float L = 0.f, w[NS];
#pragma unroll
  for (int s = 0; s < NS; ++s) {
    w[s] = exp2f(m[s] - M);
    L += l[s] * w[s];
  }
  float invL = 1.0f / L;
  float4 acc = {0.f, 0.f, 0.f, 0.f};
#pragma unroll
  for (int s = 0; s < NS; ++s) {
    float4 p = *reinterpret_cast<const float4*>(Po + ((size_t)s << 21) + (size_t)grow * 128 + c4);
    acc.x += p.x * w[s]; acc.y += p.y * w[s];
    acc.z += p.z * w[s]; acc.w += p.w * w[s];
  }
  acc.x *= invL; acc.y *= invL; acc.z *= invL; acc.w *= invL;
  *reinterpret_cast<float4*>(out + (size_t)grow * 128 + c4) = acc;
}

extern "C" void kernel_launch(void* const* d_in, const int* in_sizes, int n_in,
                              void* d_out, int out_size, void* d_ws, size_t ws_size,
                              hipStream_t stream) {
  const float* q  = (const float*)d_in[0];
  const float* k  = (const float*)d_in[1];
  const float* v  = (const float*)d_in[2];
  const float* Wq = (const float*)d_in[3];
  const float* bq = (const float*)d_in[4];
  const float* Wk = (const float*)d_in[5];
  const float* bk = (const float*)d_in[6];
  const float* Wv = (const float*)d_in[7];
  const float* bv = (const float*)d_in[8];
  float* out = (float*)d_out;

  char* ws = (char*)d_ws;
  unsigned short* Qb  = (unsigned short*)(ws);
  unsigned short* Kb  = (unsigned short*)(ws + (4u << 20));
  unsigned short* Vtb = (unsigned short*)(ws + (8u << 20));
  unsigned short* Wtq = (unsigned short*)(ws + (12u << 20));
  unsigned short* Wtk = (unsigned short*)(ws + (12u << 20) + (256u << 10));
  unsigned short* Wtv = (unsigned short*)(ws + (12u << 20) + (512u << 10));

  const size_t base = (size_t)13 << 20;
  const size_t per = ((size_t)8 << 20) + ((size_t)128 << 10);
  int nsplit = 1;
  if (ws_size >= base + 4 * per) nsplit = 4;
  else if (ws_size >= base + 2 * per) nsplit = 2;
  float* Po = (float*)(ws + base);
  float* ml = (float*)(ws + base + (size_t)nsplit * ((size_t)8 << 20));

  // diagnostic + L3-prime: stream all 192MB of q,k,v; output lands in Po
  // (fully overwritten by attn before combine reads it).
  prime_kernel<<<2048, 256, 0, stream>>>((const uint4*)q, (const uint4*)k,
                                         (const uint4*)v, (uint4*)Po);
  prep_wt_kernel<<<dim3(16, 2, 3), 256, 0, stream>>>(Wq, Wk, Wv, Wtq, Wtk, Wtv);
  proj_kernel<<<dim3(256, 3), 256, 0, stream>>>(q, k, v, Wtq, Wtk, Wtv, bq, bk, bv, Qb, Kb, Vtb);
  if (nsplit == 4) {
    attn_kernel<16><<<dim3(32, 4, 4), 256, 0, stream>>>(Qb, Kb, Vtb, Po, ml);
    combine_kernel<4><<<2048, 256, 0, stream>>>(Po, ml, out);
  } else if (nsplit == 2) {
    attn_kernel<32><<<dim3(32, 2, 4), 256, 0, stream>>>(Qb, Kb, Vtb, Po, ml);
    combine_kernel<2><<<2048, 256, 0, stream>>>(Po, ml, out);
  } else {
    attn_kernel<64><<<dim3(32, 1, 4), 256, 0, stream>>>(Qb, Kb, Vtb, Po, ml);
    combine_kernel<1><<<2048, 256, 0, stream>>>(Po, ml, out);
  }
}

// Round 14
// 107.228 us; speedup vs baseline: 1.2585x; 1.2585x over previous
//
#include <hip/hip_runtime.h>
#include <hip/hip_bf16.h>
#include <cstdint>
#include <cmath>

// Shapes (hard-coded): B=4, S=4096, D=1024, DK=DV=128.
// ws layout: Qb[16384][128]bf16 @0 (4MB) | Kb @4MB | Vt[B][128][4096]bf16 @8MB
//            | Wtq bf16[128][1024] @12MB | Wtk | Wtv (ends 12.75MB)
//            | Po16[nsplit][16384][128]bf16 @13MB | ml[nsplit][16384][2]f32 after.

typedef __bf16 bf16x8 __attribute__((ext_vector_type(8)));
typedef float f32x4 __attribute__((ext_vector_type(4)));
typedef float f32x16 __attribute__((ext_vector_type(16)));

typedef const __attribute__((address_space(1))) unsigned int* gp_t;
typedef __attribute__((address_space(3))) unsigned int* lp_t;

__device__ __forceinline__ unsigned short f2bf(float f) {
  unsigned u = __float_as_uint(f);
  u += 0x7fffu + ((u >> 16) & 1u);   // RNE
  return (unsigned short)(u >> 16);
}

__device__ __forceinline__ bf16x8 ld_frag(const char* p) {
  uint4 u = *reinterpret_cast<const uint4*>(p);
  return __builtin_bit_cast(bf16x8, u);
}

__device__ __forceinline__ unsigned cvtpk_bf16(float lo, float hi) {
  unsigned r;
  asm("v_cvt_pk_bf16_f32 %0, %1, %2" : "=v"(r) : "v"(lo), "v"(hi));
  return r;
}

__device__ __forceinline__ void pl32swap(unsigned &a, unsigned &b) {
  asm("v_permlane32_swap_b32 %0, %1" : "+v"(a), "+v"(b));
}

__device__ __forceinline__ bf16x8 mk_frag(unsigned w0, unsigned w1, unsigned w2, unsigned w3) {
  uint4 u{w0, w1, w2, w3};
  return __builtin_bit_cast(bf16x8, u);
}

__device__ __forceinline__ float bfhi2f(unsigned u) {   // high 16 bits as bf16
  return __uint_as_float(u & 0xffff0000u);
}
__device__ __forceinline__ float bflo2f(unsigned u) {   // low 16 bits as bf16
  return __uint_as_float(u << 16);
}

// Q is pre-scaled by (1/sqrt(128)) * log2(e) so softmax uses exp2 directly.
#define QSCALE_LOG2E 0.12751744f

// ---------------- W transpose: [1024][128] f32 -> [128][1024] bf16 ----------
__global__ __launch_bounds__(256) void prep_wt_kernel(
    const float* __restrict__ W0, const float* __restrict__ W1, const float* __restrict__ W2,
    unsigned short* __restrict__ T0, unsigned short* __restrict__ T1,
    unsigned short* __restrict__ T2) {
  const int mode = blockIdx.z;
  const float* W = (mode == 0) ? W0 : (mode == 1) ? W1 : W2;
  unsigned short* Wt = (mode == 0) ? T0 : (mode == 1) ? T1 : T2;
  __shared__ float tile[64][65];
  int kt = blockIdx.x, nt = blockIdx.y;   // (16, 2)
  int tid = threadIdx.x;
  int c = tid & 63;
  int r0 = (tid >> 6) * 16;
#pragma unroll
  for (int i = 0; i < 16; ++i) {
    int r = r0 + i;
    tile[r][c] = W[(size_t)(kt * 64 + r) * 128 + nt * 64 + c];
  }
  __syncthreads();
#pragma unroll
  for (int i = 0; i < 16; ++i) {
    int n = r0 + i;
    Wt[(size_t)(nt * 64 + n) * 1024 + kt * 64 + c] = f2bf(tile[c][n]);
  }
}

// ---------------- projections (fat-step, A-loads non-temporal) --------------
__global__ __launch_bounds__(256, 3) void proj_kernel(
    const float* __restrict__ qx, const float* __restrict__ kx, const float* __restrict__ vx,
    const unsigned short* __restrict__ Wtq, const unsigned short* __restrict__ Wtk,
    const unsigned short* __restrict__ Wtv,
    const float* __restrict__ bq, const float* __restrict__ bk, const float* __restrict__ bv,
    unsigned short* __restrict__ Qb, unsigned short* __restrict__ Kb,
    unsigned short* __restrict__ Vtb) {
  const int mode = blockIdx.y;  // 0=Q 1=K 2=V
  const float* x = (mode == 0) ? qx : (mode == 1) ? kx : vx;
  const unsigned short* Wt = (mode == 0) ? Wtq : (mode == 1) ? Wtk : Wtv;
  const float* bias = (mode == 0) ? bq : (mode == 1) ? bk : bv;

  __shared__ __align__(16) char lds[49152];
  char* ldsA = lds;            // [64 rows][128 k] bf16, 16KB, XOR-swizzled
  char* ldsW = lds + 16384;    // [128 n][128 k] bf16, 32KB, XOR-swizzled

  const int tid = threadIdx.x;
  const int lane = tid & 63, wid = tid >> 6;
  const int l15 = lane & 15, hi = lane >> 4;
  const long row0 = (long)blockIdx.x * 64;

  const int a_row0 = tid >> 5;
  const int a_c16  = tid & 31;
  const float* a_src = x + (row0 + a_row0) * 1024 + a_c16 * 4;
  const int a_swz = (a_row0 & 7) << 4;
  const int a_wbyte = (((a_c16 >> 1) * 16) ^ a_swz) + (a_c16 & 1) * 8;

  const char* w_src = (const char*)Wt + (size_t)(tid >> 4) * 2048 +
                      (size_t)((tid & 15) ^ ((tid >> 4) & 7)) * 16;

  f32x4 acc[8];
#pragma unroll
  for (int i = 0; i < 8; ++i) acc[i] = f32x4{0.f, 0.f, 0.f, 0.f};

  const int arow = wid * 16 + l15;
  const int aswzr = (arow & 7) << 4;

#pragma unroll 1
  for (int t = 0; t < 8; ++t) {
    f32x4 av[8];
#pragma unroll
    for (int j = 0; j < 8; ++j)
      av[j] = __builtin_nontemporal_load(
          reinterpret_cast<const f32x4*>(a_src + t * 128 + j * 8192));
#pragma unroll
    for (int i = 0; i < 8; ++i)
      __builtin_amdgcn_global_load_lds((gp_t)(w_src + (size_t)i * 32768 + t * 256),
                                       (lp_t)(ldsW + i * 4096 + wid * 1024), 16, 0, 0);
#pragma unroll
    for (int j = 0; j < 8; ++j) {
      uint2 wv;
      wv.x = cvtpk_bf16(av[j][0], av[j][1]);
      wv.y = cvtpk_bf16(av[j][2], av[j][3]);
      *reinterpret_cast<uint2*>(ldsA + a_row0 * 256 + j * 2048 + a_wbyte) = wv;
    }
    __syncthreads();

    bf16x8 af[4];
#pragma unroll
    for (int kk = 0; kk < 4; ++kk)
      af[kk] = ld_frag(ldsA + ((arow * 256 + (kk * 4 + hi) * 16) ^ aswzr));
#pragma unroll
    for (int ni = 0; ni < 8; ++ni) {
      int n = ni * 16 + l15;
      int nswz = (n & 7) << 4;
#pragma unroll
      for (int kk = 0; kk < 4; ++kk) {
        bf16x8 wf = ld_frag(ldsW + ((n * 256 + (kk * 4 + hi) * 16) ^ nswz));
        acc[ni] = __builtin_amdgcn_mfma_f32_16x16x32_bf16(af[kk], wf, acc[ni], 0, 0, 0);
      }
    }
    __syncthreads();
  }

#pragma unroll
  for (int ni = 0; ni < 8; ++ni) {
    int n = ni * 16 + l15;
    float bv_ = bias[n];
    long m = row0 + wid * 16 + hi * 4;
    f32x4 a = acc[ni];
    if (mode == 2) {
      int bb = (int)(m >> 12);
      int s = (int)(m & 4095);
      ushort4 pk;
      pk.x = f2bf(a[0] + bv_); pk.y = f2bf(a[1] + bv_);
      pk.z = f2bf(a[2] + bv_); pk.w = f2bf(a[3] + bv_);
      *reinterpret_cast<ushort4*>(Vtb + ((size_t)(bb * 128 + n)) * 4096 + s) = pk;
    } else {
      const float sc = (mode == 0) ? QSCALE_LOG2E : 1.0f;
      unsigned short* outp = (mode == 0) ? Qb : Kb;
      outp[(m + 0) * 128 + n] = f2bf((a[0] + bv_) * sc);
      outp[(m + 1) * 128 + n] = f2bf((a[1] + bv_) * sc);
      outp[(m + 2) * 128 + n] = f2bf((a[2] + bv_) * sc);
      outp[(m + 3) * 128 + n] = f2bf((a[3] + bv_) * sc);
    }
  }
}

// ---------------- flash attention (32x32 swapped, dbuf K/V + counted vmcnt) -
// Partial O stored as bf16 (halves Po write/read traffic).
template <int TPS>
__global__ __launch_bounds__(256, 2) void attn_kernel(
    const unsigned short* __restrict__ Qb, const unsigned short* __restrict__ Kb,
    const unsigned short* __restrict__ Vtb, unsigned short* __restrict__ Po,
    float* __restrict__ ml) {
  __shared__ __align__(16) char lds[65536];  // K: 2x16KB @0, V: 2x16KB @32768

  const int tid = threadIdx.x;
  const int lane = tid & 63, wid = tid >> 6;
  const int l31 = lane & 31, hi = lane >> 5;
  const int split = blockIdx.y;
  const int b = blockIdx.z;
  const int qbase = blockIdx.x * 128 + wid * 32;  // within batch
  const size_t growq = (size_t)b * 4096 + qbase + l31;

  const char* kg0 = (const char*)Kb + (size_t)(b * 4096) * 256;
  const char* vg0 = (const char*)Vtb + (size_t)b * 128 * 4096 * 2;
  const int k_row = tid >> 4;
  const int k_csw = (tid & 15) ^ (k_row & 7);
  const int v_dv = tid >> 3;
  const int v_csw = (tid & 7) ^ (v_dv & 7);

#define ATTN_STAGE(KV0, BUF)                                                          \
  {                                                                                   \
    char* kb_ = lds + (BUF) * 16384;                                                  \
    char* vb_ = lds + 32768 + (BUF) * 16384;                                          \
    const char* kgs_ = kg0 + (size_t)(KV0) * 256 + (size_t)k_row * 256 + k_csw * 16;  \
    const char* vgs_ = vg0 + (size_t)(KV0) * 2 + (size_t)v_dv * 8192 + v_csw * 16;    \
    _Pragma("unroll")                                                                 \
    for (int i = 0; i < 4; ++i)                                                       \
      __builtin_amdgcn_global_load_lds((gp_t)(kgs_ + (size_t)i * 4096),               \
                                       (lp_t)(kb_ + i * 4096 + wid * 1024), 16, 0, 0);\
    _Pragma("unroll")                                                                 \
    for (int i = 0; i < 4; ++i)                                                       \
      __builtin_amdgcn_global_load_lds((gp_t)(vgs_ + (size_t)i * 262144),             \
                                       (lp_t)(vb_ + i * 4096 + wid * 1024), 16, 0, 0);\
  }

  bf16x8 qf[8];
  {
    const unsigned short* qp = Qb + growq * 128 + hi * 8;
#pragma unroll
    for (int kt = 0; kt < 8; ++kt)
      qf[kt] = __builtin_bit_cast(bf16x8, *reinterpret_cast<const uint4*>(qp + kt * 16));
  }

  f32x16 oacc[4];
#pragma unroll
  for (int d = 0; d < 4; ++d)
#pragma unroll
    for (int j = 0; j < 16; ++j) oacc[d][j] = 0.f;
  float mrun = -INFINITY, lrun = 0.f;

  const int t0 = split * TPS, t1 = t0 + TPS;

  ATTN_STAGE(t0 * 64, 0);
  ATTN_STAGE((t0 + 1) * 64, 1);

#pragma unroll 1
  for (int t = t0; t < t1; ++t) {
    const int buf = (t - t0) & 1;
    if (t < t1 - 1) asm volatile("s_waitcnt vmcnt(8)" ::: "memory");
    else            asm volatile("s_waitcnt vmcnt(0)" ::: "memory");
    __builtin_amdgcn_s_barrier();
    __builtin_amdgcn_sched_barrier(0);
    char* ldsK = lds + buf * 16384;
    char* ldsV = lds + 32768 + buf * 16384;

    f32x16 sc0, sc1;
#pragma unroll
    for (int j = 0; j < 16; ++j) { sc0[j] = 0.f; sc1[j] = 0.f; }
    __builtin_amdgcn_s_setprio(1);
#pragma unroll
    for (int kvb = 0; kvb < 2; ++kvb) {
      int row = kvb * 32 + l31;
      int rowoff = row * 256, swz = (row & 7) << 4;
#pragma unroll
      for (int kt = 0; kt < 8; ++kt) {
        bf16x8 kf = ld_frag(ldsK + ((rowoff + kt * 32 + hi * 16) ^ swz));
        if (kvb == 0) sc0 = __builtin_amdgcn_mfma_f32_32x32x16_bf16(kf, qf[kt], sc0, 0, 0, 0);
        else          sc1 = __builtin_amdgcn_mfma_f32_32x32x16_bf16(kf, qf[kt], sc1, 0, 0, 0);
      }
    }
    __builtin_amdgcn_s_setprio(0);

    float tmx[16];
#pragma unroll
    for (int i = 0; i < 16; ++i) tmx[i] = fmaxf(sc0[i], sc1[i]);
#pragma unroll
    for (int s = 8; s > 0; s >>= 1)
#pragma unroll
      for (int i = 0; i < s; ++i) tmx[i] = fmaxf(tmx[i], tmx[i + s]);
    float mt = tmx[0];
    mt = fmaxf(mt, __shfl_xor(mt, 32));

    if (!__all(mt - mrun <= 8.0f)) {
      float mnew = fmaxf(mrun, mt);
      float scl = exp2f(mrun - mnew);
      mrun = mnew;
      lrun *= scl;
#pragma unroll
      for (int d = 0; d < 4; ++d)
#pragma unroll
        for (int j = 0; j < 16; ++j) oacc[d][j] *= scl;
    }

#pragma unroll
    for (int i = 0; i < 16; ++i) {
      sc0[i] = exp2f(sc0[i] - mrun);
      sc1[i] = exp2f(sc1[i] - mrun);
    }
    float ts[16];
#pragma unroll
    for (int i = 0; i < 16; ++i) ts[i] = sc0[i] + sc1[i];
#pragma unroll
    for (int s = 8; s > 0; s >>= 1)
#pragma unroll
      for (int i = 0; i < s; ++i) ts[i] += ts[i + s];
    float psum = ts[0];
    psum += __shfl_xor(psum, 32);
    lrun += psum;

    bf16x8 pa[4];
#pragma unroll
    for (int c = 0; c < 2; ++c) {
      const f32x16& p = c ? sc1 : sc0;
#pragma unroll
      for (int g = 0; g < 2; ++g) {
        const int base = g * 8;
        unsigned a0 = cvtpk_bf16(p[base + 0], p[base + 1]);
        unsigned b0 = cvtpk_bf16(p[base + 4], p[base + 5]);
        pl32swap(a0, b0);
        unsigned a1 = cvtpk_bf16(p[base + 2], p[base + 3]);
        unsigned b1 = cvtpk_bf16(p[base + 6], p[base + 7]);
        pl32swap(a1, b1);
        pa[c * 2 + g] = mk_frag(a0, a1, b0, b1);
      }
    }

    __builtin_amdgcn_s_setprio(1);
#pragma unroll
    for (int dvb = 0; dvb < 4; ++dvb) {
      int vrow = dvb * 32 + l31;
      int voff = vrow * 128, vswz = (vrow & 7) << 4;
#pragma unroll
      for (int tt = 0; tt < 4; ++tt) {
        bf16x8 vf = ld_frag(ldsV + ((voff + tt * 32 + hi * 16) ^ vswz));
        oacc[dvb] = __builtin_amdgcn_mfma_f32_32x32x16_bf16(vf, pa[tt], oacc[dvb], 0, 0, 0);
      }
    }
    __builtin_amdgcn_s_setprio(0);

    __builtin_amdgcn_s_barrier();
    __builtin_amdgcn_sched_barrier(0);
    if (t + 2 < t1) ATTN_STAGE((t + 2) * 64, buf);
  }

#undef ATTN_STAGE

  if (hi == 0) {
    float* mlp = ml + (size_t)split * 32768 + growq * 2;
    mlp[0] = mrun; mlp[1] = lrun;
  }

  // epilogue: O^T -> O via per-wave LDS transpose (f32), bf16 global stores
  unsigned short* po = Po + ((size_t)split << 21) + ((size_t)b * 4096 + qbase) * 128;
  char* tbase = lds + wid * 4096;
  for (int dvb = 0; dvb < 4; ++dvb) {
#pragma unroll
    for (int g = 0; g < 4; ++g) {
      float4 w4{oacc[dvb][g * 4 + 0], oacc[dvb][g * 4 + 1],
                oacc[dvb][g * 4 + 2], oacc[dvb][g * 4 + 3]};
      int off = (l31 * 128 + g * 32 + hi * 16) ^ ((l31 & 7) << 4);
      *reinterpret_cast<float4*>(tbase + off) = w4;
    }
    asm volatile("s_waitcnt lgkmcnt(0)" ::: "memory");
    __builtin_amdgcn_sched_barrier(0);
#pragma unroll
    for (int qq = 0; qq < 4; ++qq) {
      int q = qq * 8 + (lane >> 3);
      int off = (q * 128 + (lane & 7) * 16) ^ ((q & 7) << 4);
      float4 r4 = *reinterpret_cast<const float4*>(tbase + off);
      uint2 pk{cvtpk_bf16(r4.x, r4.y), cvtpk_bf16(r4.z, r4.w)};
      *reinterpret_cast<uint2*>(po + (size_t)q * 128 + dvb * 32 + (lane & 7) * 4) = pk;
    }
    asm volatile("s_waitcnt lgkmcnt(0)" ::: "memory");
    __builtin_amdgcn_sched_barrier(0);
  }
}

// ---------------- combine partials (bf16 Po) --------------------------------
template <int NS>
__global__ __launch_bounds__(256) void combine_kernel(const unsigned short* __restrict__ Po,
                                                      const float* __restrict__ ml,
                                                      float* __restrict__ out) {
  int idx = blockIdx.x * 256 + threadIdx.x;  // 16384*32 4-elem units
  int grow = idx >> 5;
  int c4 = (idx & 31) * 4;
  float m[NS], l[NS];
  float M = -INFINITY;
#pragma unroll
  for (int s = 0; s < NS; ++s) {
    m[s] = ml[(size_t)s * 32768 + grow * 2 + 0];
    l[s] = ml[(size_t)s * 32768 + grow * 2 + 1];
    M = fmaxf(M, m[s]);
  }
  float L = 0.f, w[NS];
#pragma unroll
  for (int s = 0; s < NS; ++s) {
    w[s] = exp2f(m[s] - M);   // log2 domain
    L += l[s] * w[s];
  }
  float invL = 1.0f / L;
  float4 acc = {0.f, 0.f, 0.f, 0.f};
#pragma unroll
  for (int s = 0; s < NS; ++s) {
    uint2 pv = *reinterpret_cast<const uint2*>(Po + ((size_t)s << 21) + (size_t)grow * 128 + c4);
    acc.x += bflo2f(pv.x) * w[s];
    acc.y += bfhi2f(pv.x) * w[s];
    acc.z += bflo2f(pv.y) * w[s];
    acc.w += bfhi2f(pv.y) * w[s];
  }
  acc.x *= invL; acc.y *= invL; acc.z *= invL; acc.w *= invL;
  *reinterpret_cast<float4*>(out + (size_t)grow * 128 + c4) = acc;
}

extern "C" void kernel_launch(void* const* d_in, const int* in_sizes, int n_in,
                              void* d_out, int out_size, void* d_ws, size_t ws_size,
                              hipStream_t stream) {
  const float* q  = (const float*)d_in[0];
  const float* k  = (const float*)d_in[1];
  const float* v  = (const float*)d_in[2];
  const float* Wq = (const float*)d_in[3];
  const float* bq = (const float*)d_in[4];
  const float* Wk = (const float*)d_in[5];
  const float* bk = (const float*)d_in[6];
  const float* Wv = (const float*)d_in[7];
  const float* bv = (const float*)d_in[8];
  float* out = (float*)d_out;

  char* ws = (char*)d_ws;
  unsigned short* Qb  = (unsigned short*)(ws);
  unsigned short* Kb  = (unsigned short*)(ws + (4u << 20));
  unsigned short* Vtb = (unsigned short*)(ws + (8u << 20));
  unsigned short* Wtq = (unsigned short*)(ws + (12u << 20));
  unsigned short* Wtk = (unsigned short*)(ws + (12u << 20) + (256u << 10));
  unsigned short* Wtv = (unsigned short*)(ws + (12u << 20) + (512u << 10));

  const size_t base = (size_t)13 << 20;
  const size_t per = ((size_t)4 << 20) + ((size_t)128 << 10);
  int nsplit = 1;
  if (ws_size >= base + 4 * per) nsplit = 4;
  else if (ws_size >= base + 2 * per) nsplit = 2;
  unsigned short* Po = (unsigned short*)(ws + base);
  float* ml = (float*)(ws + base + (size_t)nsplit * ((size_t)4 << 20));

  prep_wt_kernel<<<dim3(16, 2, 3), 256, 0, stream>>>(Wq, Wk, Wv, Wtq, Wtk, Wtv);
  proj_kernel<<<dim3(256, 3), 256, 0, stream>>>(q, k, v, Wtq, Wtk, Wtv, bq, bk, bv, Qb, Kb, Vtb);
  if (nsplit == 4) {
    attn_kernel<16><<<dim3(32, 4, 4), 256, 0, stream>>>(Qb, Kb, Vtb, Po, ml);
    combine_kernel<4><<<2048, 256, 0, stream>>>(Po, ml, out);
  } else if (nsplit == 2) {
    attn_kernel<32><<<dim3(32, 2, 4), 256, 0, stream>>>(Qb, Kb, Vtb, Po, ml);
    combine_kernel<2><<<2048, 256, 0, stream>>>(Po, ml, out);
  } else {
    attn_kernel<64><<<dim3(32, 1, 4), 256, 0, stream>>>(Qb, Kb, Vtb, Po, ml);
    combine_kernel<1><<<2048, 256, 0, stream>>>(Po, ml, out);
  }
}

// Round 15
// 101.696 us; speedup vs baseline: 1.3270x; 1.0544x over previous
//
#include <hip/hip_runtime.h>
#include <hip/hip_bf16.h>
#include <cstdint>
#include <cmath>

// Shapes (hard-coded): B=4, S=4096, D=1024, DK=DV=128.
// ws layout: Qb[16384][128]bf16 @0 (4MB) | Kb @4MB | Vt[B][128][4096]bf16 @8MB
//            | Wtq bf16[128][1024] @12MB | Wtk | Wtv (ends 12.75MB)
//            | Po16[nsplit][16384][128]bf16 @13MB | ml[nsplit][16384][2]f32 after.

typedef __bf16 bf16x8 __attribute__((ext_vector_type(8)));
typedef float f32x4 __attribute__((ext_vector_type(4)));
typedef float f32x16 __attribute__((ext_vector_type(16)));

typedef const __attribute__((address_space(1))) unsigned int* gp_t;
typedef __attribute__((address_space(3))) unsigned int* lp_t;

__device__ __forceinline__ unsigned short f2bf(float f) {
  unsigned u = __float_as_uint(f);
  u += 0x7fffu + ((u >> 16) & 1u);   // RNE
  return (unsigned short)(u >> 16);
}

__device__ __forceinline__ bf16x8 ld_frag(const char* p) {
  uint4 u = *reinterpret_cast<const uint4*>(p);
  return __builtin_bit_cast(bf16x8, u);
}

__device__ __forceinline__ unsigned cvtpk_bf16(float lo, float hi) {
  unsigned r;
  asm("v_cvt_pk_bf16_f32 %0, %1, %2" : "=v"(r) : "v"(lo), "v"(hi));
  return r;
}

__device__ __forceinline__ void pl32swap(unsigned &a, unsigned &b) {
  asm("v_permlane32_swap_b32 %0, %1" : "+v"(a), "+v"(b));
}

__device__ __forceinline__ bf16x8 mk_frag(unsigned w0, unsigned w1, unsigned w2, unsigned w3) {
  uint4 u{w0, w1, w2, w3};
  return __builtin_bit_cast(bf16x8, u);
}

__device__ __forceinline__ float bfhi2f(unsigned u) {   // high 16 bits as bf16
  return __uint_as_float(u & 0xffff0000u);
}
__device__ __forceinline__ float bflo2f(unsigned u) {   // low 16 bits as bf16
  return __uint_as_float(u << 16);
}

// Q is pre-scaled by (1/sqrt(128)) * log2(e) so softmax uses exp2 directly.
#define QSCALE_LOG2E 0.12751744f

// ---------------- W transpose: [1024][128] f32 -> [128][1024] bf16 ----------
__global__ __launch_bounds__(256) void prep_wt_kernel(
    const float* __restrict__ W0, const float* __restrict__ W1, const float* __restrict__ W2,
    unsigned short* __restrict__ T0, unsigned short* __restrict__ T1,
    unsigned short* __restrict__ T2) {
  const int mode = blockIdx.z;
  const float* W = (mode == 0) ? W0 : (mode == 1) ? W1 : W2;
  unsigned short* Wt = (mode == 0) ? T0 : (mode == 1) ? T1 : T2;
  __shared__ float tile[64][65];
  int kt = blockIdx.x, nt = blockIdx.y;   // (16, 2)
  int tid = threadIdx.x;
  int c = tid & 63;
  int r0 = (tid >> 6) * 16;
#pragma unroll
  for (int i = 0; i < 16; ++i) {
    int r = r0 + i;
    tile[r][c] = W[(size_t)(kt * 64 + r) * 128 + nt * 64 + c];
  }
  __syncthreads();
#pragma unroll
  for (int i = 0; i < 16; ++i) {
    int n = r0 + i;
    Wt[(size_t)(nt * 64 + n) * 1024 + kt * 64 + c] = f2bf(tile[c][n]);
  }
}

// ---------------- projections (fat-step; nt reverted) -----------------------
__global__ __launch_bounds__(256, 3) void proj_kernel(
    const float* __restrict__ qx, const float* __restrict__ kx, const float* __restrict__ vx,
    const unsigned short* __restrict__ Wtq, const unsigned short* __restrict__ Wtk,
    const unsigned short* __restrict__ Wtv,
    const float* __restrict__ bq, const float* __restrict__ bk, const float* __restrict__ bv,
    unsigned short* __restrict__ Qb, unsigned short* __restrict__ Kb,
    unsigned short* __restrict__ Vtb) {
  const int mode = blockIdx.y;  // 0=Q 1=K 2=V
  const float* x = (mode == 0) ? qx : (mode == 1) ? kx : vx;
  const unsigned short* Wt = (mode == 0) ? Wtq : (mode == 1) ? Wtk : Wtv;
  const float* bias = (mode == 0) ? bq : (mode == 1) ? bk : bv;

  __shared__ __align__(16) char lds[49152];
  char* ldsA = lds;            // [64 rows][128 k] bf16, 16KB, XOR-swizzled
  char* ldsW = lds + 16384;    // [128 n][128 k] bf16, 32KB, XOR-swizzled

  const int tid = threadIdx.x;
  const int lane = tid & 63, wid = tid >> 6;
  const int l15 = lane & 15, hi = lane >> 4;
  const long row0 = (long)blockIdx.x * 64;

  const int a_row0 = tid >> 5;
  const int a_c16  = tid & 31;
  const float* a_src = x + (row0 + a_row0) * 1024 + a_c16 * 4;
  const int a_swz = (a_row0 & 7) << 4;
  const int a_wbyte = (((a_c16 >> 1) * 16) ^ a_swz) + (a_c16 & 1) * 8;

  const char* w_src = (const char*)Wt + (size_t)(tid >> 4) * 2048 +
                      (size_t)((tid & 15) ^ ((tid >> 4) & 7)) * 16;

  f32x4 acc[8];
#pragma unroll
  for (int i = 0; i < 8; ++i) acc[i] = f32x4{0.f, 0.f, 0.f, 0.f};

  const int arow = wid * 16 + l15;
  const int aswzr = (arow & 7) << 4;

#pragma unroll 1
  for (int t = 0; t < 8; ++t) {
    f32x4 av[8];
#pragma unroll
    for (int j = 0; j < 8; ++j)
      av[j] = *reinterpret_cast<const f32x4*>(a_src + t * 128 + j * 8192);
#pragma unroll
    for (int i = 0; i < 8; ++i)
      __builtin_amdgcn_global_load_lds((gp_t)(w_src + (size_t)i * 32768 + t * 256),
                                       (lp_t)(ldsW + i * 4096 + wid * 1024), 16, 0, 0);
#pragma unroll
    for (int j = 0; j < 8; ++j) {
      uint2 wv;
      wv.x = cvtpk_bf16(av[j][0], av[j][1]);
      wv.y = cvtpk_bf16(av[j][2], av[j][3]);
      *reinterpret_cast<uint2*>(ldsA + a_row0 * 256 + j * 2048 + a_wbyte) = wv;
    }
    __syncthreads();

    bf16x8 af[4];
#pragma unroll
    for (int kk = 0; kk < 4; ++kk)
      af[kk] = ld_frag(ldsA + ((arow * 256 + (kk * 4 + hi) * 16) ^ aswzr));
#pragma unroll
    for (int ni = 0; ni < 8; ++ni) {
      int n = ni * 16 + l15;
      int nswz = (n & 7) << 4;
#pragma unroll
      for (int kk = 0; kk < 4; ++kk) {
        bf16x8 wf = ld_frag(ldsW + ((n * 256 + (kk * 4 + hi) * 16) ^ nswz));
        acc[ni] = __builtin_amdgcn_mfma_f32_16x16x32_bf16(af[kk], wf, acc[ni], 0, 0, 0);
      }
    }
    __syncthreads();
  }

#pragma unroll
  for (int ni = 0; ni < 8; ++ni) {
    int n = ni * 16 + l15;
    float bv_ = bias[n];
    long m = row0 + wid * 16 + hi * 4;
    f32x4 a = acc[ni];
    if (mode == 2) {
      int bb = (int)(m >> 12);
      int s = (int)(m & 4095);
      ushort4 pk;
      pk.x = f2bf(a[0] + bv_); pk.y = f2bf(a[1] + bv_);
      pk.z = f2bf(a[2] + bv_); pk.w = f2bf(a[3] + bv_);
      *reinterpret_cast<ushort4*>(Vtb + ((size_t)(bb * 128 + n)) * 4096 + s) = pk;
    } else {
      const float sc = (mode == 0) ? QSCALE_LOG2E : 1.0f;
      unsigned short* outp = (mode == 0) ? Qb : Kb;
      outp[(m + 0) * 128 + n] = f2bf((a[0] + bv_) * sc);
      outp[(m + 1) * 128 + n] = f2bf((a[1] + bv_) * sc);
      outp[(m + 2) * 128 + n] = f2bf((a[2] + bv_) * sc);
      outp[(m + 3) * 128 + n] = f2bf((a[3] + bv_) * sc);
    }
  }
}

// ---------------- flash attention: conflict-free LDS layout -----------------
// K: [64 rows][16 slots of 16B], stored slot' = slot ^ (row&15) -> 2-way max.
// V: pair-packed [64 j][16 slots]: LDS row j holds dv=2j (slots 0-7) and
//    dv=2j+1 (slots 8-15); stored slot' = slot ^ (j&15) -> 2-way max.
// Staging: linear gload_lds dest + inverse-permuted global source (slot XOR
// is thread-constant: (tid&15)^(tid>>4)).
template <int TPS>
__global__ __launch_bounds__(256, 2) void attn_kernel(
    const unsigned short* __restrict__ Qb, const unsigned short* __restrict__ Kb,
    const unsigned short* __restrict__ Vtb, unsigned short* __restrict__ Po,
    float* __restrict__ ml) {
  __shared__ __align__(16) char lds[65536];  // K: 2x16KB @0, V: 2x16KB @32768

  const int tid = threadIdx.x;
  const int lane = tid & 63, wid = tid >> 6;
  const int l31 = lane & 31, hi = lane >> 5;
  const int split = blockIdx.y;
  const int b = blockIdx.z;
  const int qbase = blockIdx.x * 128 + wid * 32;  // within batch
  const size_t growq = (size_t)b * 4096 + qbase + l31;

  const char* kg0 = (const char*)Kb + (size_t)(b * 4096) * 256;
  const char* vg0 = (const char*)Vtb + (size_t)b * 128 * 4096 * 2;
  // staging constants (dest unit u = i*256+tid; slog = (u&15)^((u>>4)&15))
  const int k_row = tid >> 4;                       // + i*16
  const int slog  = (tid & 15) ^ (tid >> 4);        // thread-constant
  const int v_dv0 = 2 * (tid >> 4) + (slog >> 3);   // + i*32
  const int v_ksl = slog & 7;

#define ATTN_STAGE(KV0, BUF)                                                          \
  {                                                                                   \
    char* kb_ = lds + (BUF) * 16384;                                                  \
    char* vb_ = lds + 32768 + (BUF) * 16384;                                          \
    const char* kgs_ = kg0 + (size_t)(KV0) * 256 + (size_t)k_row * 256 + slog * 16;   \
    const char* vgs_ = vg0 + (size_t)(KV0) * 2 + (size_t)v_dv0 * 8192 + v_ksl * 16;   \
    _Pragma("unroll")                                                                 \
    for (int i = 0; i < 4; ++i)                                                       \
      __builtin_amdgcn_global_load_lds((gp_t)(kgs_ + (size_t)i * 4096),               \
                                       (lp_t)(kb_ + i * 4096 + wid * 1024), 16, 0, 0);\
    _Pragma("unroll")                                                                 \
    for (int i = 0; i < 4; ++i)                                                       \
      __builtin_amdgcn_global_load_lds((gp_t)(vgs_ + (size_t)i * 262144),             \
                                       (lp_t)(vb_ + i * 4096 + wid * 1024), 16, 0, 0);\
  }

  bf16x8 qf[8];
  {
    const unsigned short* qp = Qb + growq * 128 + hi * 8;
#pragma unroll
    for (int kt = 0; kt < 8; ++kt)
      qf[kt] = __builtin_bit_cast(bf16x8, *reinterpret_cast<const uint4*>(qp + kt * 16));
  }

  f32x16 oacc[4];
#pragma unroll
  for (int d = 0; d < 4; ++d)
#pragma unroll
    for (int j = 0; j < 16; ++j) oacc[d][j] = 0.f;
  float mrun = -INFINITY, lrun = 0.f;

  const int t0 = split * TPS, t1 = t0 + TPS;

  ATTN_STAGE(t0 * 64, 0);
  ATTN_STAGE((t0 + 1) * 64, 1);

  // read-side constants
  const int kswz = l31 & 15;        // K row&15
  const int vjx  = l31 >> 1;        // V LDS row (within 16-group) = j&15
  const int vslb = (l31 & 1) << 3;  // V slot base (which 128B half)

#pragma unroll 1
  for (int t = t0; t < t1; ++t) {
    const int buf = (t - t0) & 1;
    if (t < t1 - 1) asm volatile("s_waitcnt vmcnt(8)" ::: "memory");
    else            asm volatile("s_waitcnt vmcnt(0)" ::: "memory");
    __builtin_amdgcn_s_barrier();
    __builtin_amdgcn_sched_barrier(0);
    char* ldsK = lds + buf * 16384;
    char* ldsV = lds + 32768 + buf * 16384;

    f32x16 sc0, sc1;
#pragma unroll
    for (int j = 0; j < 16; ++j) { sc0[j] = 0.f; sc1[j] = 0.f; }
    __builtin_amdgcn_s_setprio(1);
#pragma unroll
    for (int kvb = 0; kvb < 2; ++kvb) {
      int rowoff = (kvb * 32 + l31) * 256;
#pragma unroll
      for (int kt = 0; kt < 8; ++kt) {
        bf16x8 kf = ld_frag(ldsK + rowoff + ((((kt << 1) + hi) ^ kswz) << 4));
        if (kvb == 0) sc0 = __builtin_amdgcn_mfma_f32_32x32x16_bf16(kf, qf[kt], sc0, 0, 0, 0);
        else          sc1 = __builtin_amdgcn_mfma_f32_32x32x16_bf16(kf, qf[kt], sc1, 0, 0, 0);
      }
    }
    __builtin_amdgcn_s_setprio(0);

    float tmx[16];
#pragma unroll
    for (int i = 0; i < 16; ++i) tmx[i] = fmaxf(sc0[i], sc1[i]);
#pragma unroll
    for (int s = 8; s > 0; s >>= 1)
#pragma unroll
      for (int i = 0; i < s; ++i) tmx[i] = fmaxf(tmx[i], tmx[i + s]);
    float mt = tmx[0];
    mt = fmaxf(mt, __shfl_xor(mt, 32));

    if (!__all(mt - mrun <= 8.0f)) {
      float mnew = fmaxf(mrun, mt);
      float scl = exp2f(mrun - mnew);
      mrun = mnew;
      lrun *= scl;
#pragma unroll
      for (int d = 0; d < 4; ++d)
#pragma unroll
        for (int j = 0; j < 16; ++j) oacc[d][j] *= scl;
    }

#pragma unroll
    for (int i = 0; i < 16; ++i) {
      sc0[i] = exp2f(sc0[i] - mrun);
      sc1[i] = exp2f(sc1[i] - mrun);
    }
    float ts[16];
#pragma unroll
    for (int i = 0; i < 16; ++i) ts[i] = sc0[i] + sc1[i];
#pragma unroll
    for (int s = 8; s > 0; s >>= 1)
#pragma unroll
      for (int i = 0; i < s; ++i) ts[i] += ts[i + s];
    float psum = ts[0];
    psum += __shfl_xor(psum, 32);
    lrun += psum;

    bf16x8 pa[4];
#pragma unroll
    for (int c = 0; c < 2; ++c) {
      const f32x16& p = c ? sc1 : sc0;
#pragma unroll
      for (int g = 0; g < 2; ++g) {
        const int base = g * 8;
        unsigned a0 = cvtpk_bf16(p[base + 0], p[base + 1]);
        unsigned b0 = cvtpk_bf16(p[base + 4], p[base + 5]);
        pl32swap(a0, b0);
        unsigned a1 = cvtpk_bf16(p[base + 2], p[base + 3]);
        unsigned b1 = cvtpk_bf16(p[base + 6], p[base + 7]);
        pl32swap(a1, b1);
        pa[c * 2 + g] = mk_frag(a0, a1, b0, b1);
      }
    }

    __builtin_amdgcn_s_setprio(1);
#pragma unroll
    for (int dvb = 0; dvb < 4; ++dvb) {
      int jbase = (dvb * 16 + vjx) * 256;
#pragma unroll
      for (int tt = 0; tt < 4; ++tt) {
        bf16x8 vf = ld_frag(ldsV + jbase + (((vslb + tt * 2 + hi) ^ vjx) << 4));
        oacc[dvb] = __builtin_amdgcn_mfma_f32_32x32x16_bf16(vf, pa[tt], oacc[dvb], 0, 0, 0);
      }
    }
    __builtin_amdgcn_s_setprio(0);

    __builtin_amdgcn_s_barrier();
    __builtin_amdgcn_sched_barrier(0);
    if (t + 2 < t1) ATTN_STAGE((t + 2) * 64, buf);
  }

#undef ATTN_STAGE

  if (hi == 0) {
    float* mlp = ml + (size_t)split * 32768 + growq * 2;
    mlp[0] = mrun; mlp[1] = lrun;
  }

  // epilogue: O^T -> O via per-wave LDS transpose (f32), bf16 global stores.
  // Scratch at lds[wid*4096] lies in K-buf 0; last tile used buf 1 (TPS even).
  unsigned short* po = Po + ((size_t)split << 21) + ((size_t)b * 4096 + qbase) * 128;
  char* tbase = lds + wid * 4096;
  for (int dvb = 0; dvb < 4; ++dvb) {
#pragma unroll
    for (int g = 0; g < 4; ++g) {
      float4 w4{oacc[dvb][g * 4 + 0], oacc[dvb][g * 4 + 1],
                oacc[dvb][g * 4 + 2], oacc[dvb][g * 4 + 3]};
      int off = (l31 * 128 + g * 32 + hi * 16) ^ ((l31 & 7) << 4);
      *reinterpret_cast<float4*>(tbase + off) = w4;
    }
    asm volatile("s_waitcnt lgkmcnt(0)" ::: "memory");
    __builtin_amdgcn_sched_barrier(0);
#pragma unroll
    for (int qq = 0; qq < 4; ++qq) {
      int q = qq * 8 + (lane >> 3);
      int off = (q * 128 + (lane & 7) * 16) ^ ((q & 7) << 4);
      float4 r4 = *reinterpret_cast<const float4*>(tbase + off);
      uint2 pk{cvtpk_bf16(r4.x, r4.y), cvtpk_bf16(r4.z, r4.w)};
      *reinterpret_cast<uint2*>(po + (size_t)q * 128 + dvb * 32 + (lane & 7) * 4) = pk;
    }
    asm volatile("s_waitcnt lgkmcnt(0)" ::: "memory");
    __builtin_amdgcn_sched_barrier(0);
  }
}

// ---------------- combine partials (bf16 Po) --------------------------------
template <int NS>
__global__ __launch_bounds__(256) void combine_kernel(const unsigned short* __restrict__ Po,
                                                      const float* __restrict__ ml,
                                                      float* __restrict__ out) {
  int idx = blockIdx.x * 256 + threadIdx.x;  // 16384*32 4-elem units
  int grow = idx >> 5;
  int c4 = (idx & 31) * 4;
  float m[NS], l[NS];
  float M = -INFINITY;
#pragma unroll
  for (int s = 0; s < NS; ++s) {
    m[s] = ml[(size_t)s * 32768 + grow * 2 + 0];
    l[s] = ml[(size_t)s * 32768 + grow * 2 + 1];
    M = fmaxf(M, m[s]);
  }
  float L = 0.f, w[NS];
#pragma unroll
  for (int s = 0; s < NS; ++s) {
    w[s] = exp2f(m[s] - M);   // log2 domain
    L += l[s] * w[s];
  }
  float invL = 1.0f / L;
  float4 acc = {0.f, 0.f, 0.f, 0.f};
#pragma unroll
  for (int s = 0; s < NS; ++s) {
    uint2 pv = *reinterpret_cast<const uint2*>(Po + ((size_t)s << 21) + (size_t)grow * 128 + c4);
    acc.x += bflo2f(pv.x) * w[s];
    acc.y += bfhi2f(pv.x) * w[s];
    acc.z += bflo2f(pv.y) * w[s];
    acc.w += bfhi2f(pv.y) * w[s];
  }
  acc.x *= invL; acc.y *= invL; acc.z *= invL; acc.w *= invL;
  *reinterpret_cast<float4*>(out + (size_t)grow * 128 + c4) = acc;
}

extern "C" void kernel_launch(void* const* d_in, const int* in_sizes, int n_in,
                              void* d_out, int out_size, void* d_ws, size_t ws_size,
                              hipStream_t stream) {
  const float* q  = (const float*)d_in[0];
  const float* k  = (const float*)d_in[1];
  const float* v  = (const float*)d_in[2];
  const float* Wq = (const float*)d_in[3];
  const float* bq = (const float*)d_in[4];
  const float* Wk = (const float*)d_in[5];
  const float* bk = (const float*)d_in[6];
  const float* Wv = (const float*)d_in[7];
  const float* bv = (const float*)d_in[8];
  float* out = (float*)d_out;

  char* ws = (char*)d_ws;
  unsigned short* Qb  = (unsigned short*)(ws);
  unsigned short* Kb  = (unsigned short*)(ws + (4u << 20));
  unsigned short* Vtb = (unsigned short*)(ws + (8u << 20));
  unsigned short* Wtq = (unsigned short*)(ws + (12u << 20));
  unsigned short* Wtk = (unsigned short*)(ws + (12u << 20) + (256u << 10));
  unsigned short* Wtv = (unsigned short*)(ws + (12u << 20) + (512u << 10));

  const size_t base = (size_t)13 << 20;
  const size_t per = ((size_t)4 << 20) + ((size_t)128 << 10);
  int nsplit = 1;
  if (ws_size >= base + 4 * per) nsplit = 4;
  else if (ws_size >= base + 2 * per) nsplit = 2;
  unsigned short* Po = (unsigned short*)(ws + base);
  float* ml = (float*)(ws + base + (size_t)nsplit * ((size_t)4 << 20));

  prep_wt_kernel<<<dim3(16, 2, 3), 256, 0, stream>>>(Wq, Wk, Wv, Wtq, Wtk, Wtv);
  proj_kernel<<<dim3(256, 3), 256, 0, stream>>>(q, k, v, Wtq, Wtk, Wtv, bq, bk, bv, Qb, Kb, Vtb);
  if (nsplit == 4) {
    attn_kernel<16><<<dim3(32, 4, 4), 256, 0, stream>>>(Qb, Kb, Vtb, Po, ml);
    combine_kernel<4><<<2048, 256, 0, stream>>>(Po, ml, out);
  } else if (nsplit == 2) {
    attn_kernel<32><<<dim3(32, 2, 4), 256, 0, stream>>>(Qb, Kb, Vtb, Po, ml);
    combine_kernel<2><<<2048, 256, 0, stream>>>(Po, ml, out);
  } else {
    attn_kernel<64><<<dim3(32, 1, 4), 256, 0, stream>>>(Qb, Kb, Vtb, Po, ml);
    combine_kernel<1><<<2048, 256, 0, stream>>>(Po, ml, out);
  }
}